// Round 8
// baseline (232.374 us; speedup 1.0000x reference)
//
#include <hip/hip_runtime.h>

// CQT on gfx950 — v8: 2 blocks/CU cqt, bounded A-prefetch pipeline, b128 B-reads.
//   Wr[b,n] = sum_k kr[b,k]*wcos[k,n] - ki[b,k]*wsin[k,n]
//   Wi[b,n] = sum_k kr[b,k]*wsin[k,n] + ki[b,k]*wcos[k,n]
//   cqt[b,f] = sqrt((sum_n x[512f+n]*W[2b,n])^2 + (sum_n x[512f+n]*W[2b+1,n])^2)
// K1 aprep:   Apf = A'[192][2208] bf16, MFMA-frag order [mt][k16][lane]x8.
// K2 wgemm:   Pp[6][192][2048] f32 partials (6mt x 64nt x 6 Ksplit, 1-wave blocks).
// K3 combine: Wpf bf16 = sum_s Pp[s], frag order [mg][k16][lane]x8.
// K4 cqt:     block 192 rows x 32 frames (xl 36.4KB -> 2 blocks/CU), 6 waves
//             (mg=w), mfma 32x32x16, A from Wpf (coalesced, depth-8 dbuf),
//             B single ds_read_b128, barrier-free K-loop.

#define HOPS 512
#define NBINS 84
#define FREQB 1025
#define FFTLEN 2048
#define NFRAMES 16381
#define TSAMP 8388608
#define SPAN32 17920          // 31*512 + 2048
#define XL32 18200            // SPAN32 + 8*(SPAN32/512)
#define KP16 138
#define WSLICE 23
#define NSPL 6

typedef short bf16x8 __attribute__((ext_vector_type(8)));
typedef float f32x16 __attribute__((ext_vector_type(16)));

union B8 { struct { ushort4 lo, hi; } p; bf16x8 v; uint4 u; };

__device__ __forceinline__ unsigned short f32_to_bf16(float f) {
    union { float f; unsigned u; } v; v.f = f;
    return (unsigned short)((v.u + 0x7FFFu + ((v.u >> 16) & 1u)) >> 16);
}
__device__ __forceinline__ unsigned pk_bf16(float lo, float hi) {
    return (unsigned)f32_to_bf16(lo) | ((unsigned)f32_to_bf16(hi) << 16);
}
__device__ __forceinline__ bf16x8 pack8(const float* s) {
    B8 r;
    r.u.x = pk_bf16(s[0], s[1]); r.u.y = pk_bf16(s[2], s[3]);
    r.u.z = pk_bf16(s[4], s[5]); r.u.w = pk_bf16(s[6], s[7]);
    return r.v;
}

// ---------------- K1: A' prep into frag order ----------------
__global__ __launch_bounds__(64) void aprep_kernel(
    const float* __restrict__ kr, const float* __restrict__ ki,
    unsigned short* __restrict__ Apf)
{
    const int bid = blockIdx.x;
    const int mt = bid / KP16, k16 = bid % KP16;
    const int l = threadIdx.x;
    const int c32 = l & 31, h = l >> 5;
    const int row = mt * 32 + c32;
    const int b = row >> 1, im = row & 1;
    const bool bok = b < NBINS;
    const float* cosp = (im ? ki : kr) + (size_t)(bok ? b : 0) * FREQB;
    const float* sinp = (im ? kr : ki) + (size_t)(bok ? b : 0) * FREQB;
    const float ssign = im ? 1.f : -1.f;

    unsigned short o[8];
    #pragma unroll
    for (int j = 0; j < 8; ++j) {
        int k = k16 * 16 + h * 8 + j;
        float v = 0.f;
        if (bok) {
            if (k <= 1024)       v = cosp[k];
            else if (k <= 2049)  v = ssign * sinp[k - 1025];
        }
        o[j] = f32_to_bf16(v);
    }
    #pragma unroll
    for (int j = 0; j < 8; ++j)
        Apf[(size_t)bid * 512 + l * 8 + j] = o[j];
}

// ---------------- K2: W GEMM partials ----------------
__global__ __launch_bounds__(64) void wgemm_kernel(
    const float* __restrict__ wcos, const float* __restrict__ wsin,
    const unsigned short* __restrict__ Apf, float* __restrict__ Pp)
{
    const int bid = blockIdx.x;
    const int nt = bid & 63;
    const int rest = bid >> 6;
    const int mt = rest % 6, s = rest / 6;
    const int l = threadIdx.x;
    const int c32 = l & 31, h = l >> 5;
    const int n = nt * 32 + c32;

    f32x16 acc;
    #pragma unroll
    for (int i = 0; i < 16; ++i) acc[i] = 0.f;

    const unsigned short* ap = Apf + (size_t)(mt * KP16 + s * WSLICE) * 512 + l * 8;

    for (int i = 0; i < WSLICE; ++i) {
        const int k16 = s * WSLICE + i;
        if (k16 > 128) break;
        B8 af; af.u = *(const uint4*)(ap + (size_t)i * 512);
        float bv[8];
        const int kb = k16 * 16 + h * 8;
        if (k16 <= 63) {
            #pragma unroll
            for (int j = 0; j < 8; ++j)
                bv[j] = wcos[(size_t)(kb + j) * FFTLEN + n];
        } else if (k16 >= 65 && k16 <= 127) {
            const int mb = kb - 1025;
            #pragma unroll
            for (int j = 0; j < 8; ++j)
                bv[j] = wsin[(size_t)(mb + j) * FFTLEN + n];
        } else {
            #pragma unroll
            for (int j = 0; j < 8; ++j) {
                int k = kb + j;
                float t = 0.f;
                if (k <= 1024)      t = wcos[(size_t)k * FFTLEN + n];
                else if (k <= 2049) t = wsin[(size_t)(k - 1025) * FFTLEN + n];
                bv[j] = t;
            }
        }
        acc = __builtin_amdgcn_mfma_f32_32x32x16_bf16(af.v, pack8(bv), acc, 0, 0, 0);
    }

    float* dst = Pp + (size_t)s * (192 * FFTLEN);
    #pragma unroll
    for (int r = 0; r < 16; ++r) {
        int row = mt * 32 + (r & 3) + 8 * (r >> 2) + 4 * h;
        dst[(size_t)row * FFTLEN + n] = acc[r];
    }
}

// ---------------- K3: combine partials -> Wpf (frag order) ----------------
__global__ __launch_bounds__(256) void combine_kernel(
    const float* __restrict__ Pp, unsigned short* __restrict__ Wpf)
{
    const int gid = blockIdx.x * 256 + threadIdx.x;   // < 49152
    const int mg = gid >> 13;
    const int r = gid & 8191;
    const int k16 = r >> 6, l = r & 63;
    const int c32 = l & 31, h = l >> 5;
    const int row = mg * 32 + c32;
    const int n0 = k16 * 16 + h * 8;

    float4 s0 = make_float4(0.f, 0.f, 0.f, 0.f), s1 = s0;
    const float* base = Pp + (size_t)row * FFTLEN + n0;
    #pragma unroll
    for (int s = 0; s < NSPL; ++s) {
        const float* p = base + (size_t)s * (192 * FFTLEN);
        float4 a = *(const float4*)(p);
        float4 b = *(const float4*)(p + 4);
        s0.x += a.x; s0.y += a.y; s0.z += a.z; s0.w += a.w;
        s1.x += b.x; s1.y += b.y; s1.z += b.z; s1.w += b.w;
    }
    uint4 o;
    o.x = pk_bf16(s0.x, s0.y); o.y = pk_bf16(s0.z, s0.w);
    o.z = pk_bf16(s1.x, s1.y); o.w = pk_bf16(s1.z, s1.w);
    ((uint4*)Wpf)[gid] = o;
}

// ---------------- K4: main GEMM ----------------
// grid 512 x 384 (6 waves). Block: frames f0..f0+31, all 192 rows. Wave w = mg.
// xl layout: addr16(s) = s + 8*(s>>9) — 16B-aligned frags, uniform banks.
__global__ __launch_bounds__(384) void cqt_kernel(
    const float* __restrict__ x, const unsigned short* __restrict__ Wpf,
    float* __restrict__ out)
{
    __shared__ __align__(16) unsigned short xl[XL32];   // 36,400 B

    const int t = threadIdx.x;
    const int f0 = blockIdx.x * 32;
    const long S0 = (long)f0 * HOPS;
    const int valid = (int)((TSAMP - S0) < (long)SPAN32 ? (TSAMP - S0) : (long)SPAN32);

    // stage x-span once: 4480 float4 over 384 threads
    #pragma unroll
    for (int i = 0; i < 12; ++i) {
        int idx4 = t + i * 384;
        if (idx4 < 4480) {
            int s = idx4 * 4;
            float4 v = make_float4(0.f, 0.f, 0.f, 0.f);
            if (s + 4 <= valid) v = *(const float4*)(x + S0 + s);
            ushort4 o;
            o.x = f32_to_bf16(v.x); o.y = f32_to_bf16(v.y);
            o.z = f32_to_bf16(v.z); o.w = f32_to_bf16(v.w);
            *(ushort4*)(&xl[s + 8 * (s >> 9)]) = o;
        }
    }
    __syncthreads();   // the only barrier

    const int w = t >> 6, l = t & 63;       // w = mg (0..5)
    const int c32 = l & 31, h = l >> 5;

    const unsigned short* apf = Wpf + (size_t)w * (128 * 512) + l * 8;  // + k16*512
    const int sbase = c32 * HOPS + h * 8;

    f32x16 acc;
    #pragma unroll
    for (int i = 0; i < 16; ++i) acc[i] = 0.f;

    auto ldsB = [&](int k16) -> bf16x8 {
        int s = sbase + k16 * 16;
        int off = s + 8 * (s >> 9);
        B8 r; r.u = *(const uint4*)(&xl[off]);   // single b128, 16B-aligned
        return r.v;
    };

    uint4 Abuf[2][8];
    #pragma unroll
    for (int j = 0; j < 8; ++j)
        Abuf[0][j] = *(const uint4*)(apf + (size_t)j * 512);

    #pragma unroll 1
    for (int c = 0; c < 16; ++c) {
        const int cur = c & 1, nxt = cur ^ 1;
        if (c < 15) {
            #pragma unroll
            for (int j = 0; j < 8; ++j)
                Abuf[nxt][j] = *(const uint4*)(apf + (size_t)((c + 1) * 8 + j) * 512);
        }
        #pragma unroll
        for (int j = 0; j < 8; ++j) {
            B8 af; af.u = Abuf[cur][j];
            acc = __builtin_amdgcn_mfma_f32_32x32x16_bf16(af.v, ldsB(c * 8 + j), acc, 0, 0, 0);
        }
    }

    // epilogue: C/D col=c32 (f), row=(r&3)+8*(r>>2)+4*h; (Wr,Wi) pairs -> magnitude
    const int f = f0 + c32;
    if (f < NFRAMES) {
        #pragma unroll
        for (int rp = 0; rp < 4; ++rp) {
            int base = w * 32 + 8 * rp + 4 * h;   // even
            int b0 = base >> 1;
            float r0 = acc[4 * rp + 0], i0 = acc[4 * rp + 1];
            float r1 = acc[4 * rp + 2], i1 = acc[4 * rp + 3];
            if (b0 < NBINS)
                out[(size_t)b0 * NFRAMES + f] = sqrtf(r0 * r0 + i0 * i0);
            if (b0 + 1 < NBINS)
                out[(size_t)(b0 + 1) * NFRAMES + f] = sqrtf(r1 * r1 + i1 * i1);
        }
    }
}

extern "C" void kernel_launch(void* const* d_in, const int* in_sizes, int n_in,
                              void* d_out, int out_size, void* d_ws, size_t ws_size,
                              hipStream_t stream) {
    const float* x    = (const float*)d_in[0];
    const float* wcos = (const float*)d_in[1];
    const float* wsin = (const float*)d_in[2];
    const float* kr   = (const float*)d_in[3];
    const float* ki   = (const float*)d_in[4];
    float* out = (float*)d_out;

    unsigned short* Wpf = (unsigned short*)d_ws;                    //   786,432 B
    unsigned short* Apf = (unsigned short*)((char*)d_ws + 786432);  //   847,872 B
    float* Pp = (float*)((char*)d_ws + 786432 + 847872);            // 9,437,184 B

    aprep_kernel<<<dim3(6 * KP16), dim3(64), 0, stream>>>(kr, ki, Apf);
    wgemm_kernel<<<dim3(2304), dim3(64), 0, stream>>>(wcos, wsin, Apf, Pp);
    combine_kernel<<<dim3(192), dim3(256), 0, stream>>>(Pp, Wpf);
    cqt_kernel<<<dim3(512), dim3(384), 0, stream>>>(x, Wpf, out);
}

// Round 9
// 132.784 us; speedup vs baseline: 1.7500x; 1.7500x over previous
//
#include <hip/hip_runtime.h>

// CQT on gfx950 — v9: v8 with the cqt scratch-spill fixed (static ping-pong),
// 64-frame blocks (nt=2/wave), pad-4 LDS + b64 pairs (0-conflict layout from R6).
//   Wr[b,n] = sum_k kr[b,k]*wcos[k,n] - ki[b,k]*wsin[k,n]
//   Wi[b,n] = sum_k kr[b,k]*wsin[k,n] + ki[b,k]*wcos[k,n]
//   cqt[b,f] = sqrt((sum_n x[512f+n]*W[2b,n])^2 + (sum_n x[512f+n]*W[2b+1,n])^2)
// K1 aprep:   Apf = A'[192][2208] bf16, MFMA-frag order [mt][k16][lane]x8.
// K2 wgemm:   Pp[6][192][2048] f32 partials (6mt x 64nt x 6 Ksplit, 1-wave blocks).
// K3 combine: Wpf bf16 = sum_s Pp[s], frag order [mg][k16][lane]x8.
// K4 cqt:     block 192 rows x 64 frames, 6 waves (w=mg, nt=2), mfma 32x32x16,
//             A from Wpf coalesced w/ explicit ping-pong (REGISTERS: all indices
//             static), B via 2x ds_read_b64, barrier-free K-loop, 2 blocks/CU.

#define HOPS 512
#define NBINS 84
#define FREQB 1025
#define FFTLEN 2048
#define NFRAMES 16381
#define TSAMP 8388608
#define SPAN 34304            // 63*512 + 2048
#define XLSZ 34576            // SPAN + 4*(SPAN/512) = 34304 + 268 -> round up
#define KP16 138
#define WSLICE 23
#define NSPL 6

typedef short bf16x8 __attribute__((ext_vector_type(8)));
typedef float f32x16 __attribute__((ext_vector_type(16)));

union B8 { struct { ushort4 lo, hi; } p; bf16x8 v; uint4 u; };

__device__ __forceinline__ unsigned short f32_to_bf16(float f) {
    union { float f; unsigned u; } v; v.f = f;
    return (unsigned short)((v.u + 0x7FFFu + ((v.u >> 16) & 1u)) >> 16);
}
__device__ __forceinline__ unsigned pk_bf16(float lo, float hi) {
    return (unsigned)f32_to_bf16(lo) | ((unsigned)f32_to_bf16(hi) << 16);
}
__device__ __forceinline__ bf16x8 pack8(const float* s) {
    B8 r;
    r.u.x = pk_bf16(s[0], s[1]); r.u.y = pk_bf16(s[2], s[3]);
    r.u.z = pk_bf16(s[4], s[5]); r.u.w = pk_bf16(s[6], s[7]);
    return r.v;
}

// ---------------- K1: A' prep into frag order ----------------
__global__ __launch_bounds__(64) void aprep_kernel(
    const float* __restrict__ kr, const float* __restrict__ ki,
    unsigned short* __restrict__ Apf)
{
    const int bid = blockIdx.x;
    const int mt = bid / KP16, k16 = bid % KP16;
    const int l = threadIdx.x;
    const int c32 = l & 31, h = l >> 5;
    const int row = mt * 32 + c32;
    const int b = row >> 1, im = row & 1;
    const bool bok = b < NBINS;
    const float* cosp = (im ? ki : kr) + (size_t)(bok ? b : 0) * FREQB;
    const float* sinp = (im ? kr : ki) + (size_t)(bok ? b : 0) * FREQB;
    const float ssign = im ? 1.f : -1.f;

    unsigned short o[8];
    #pragma unroll
    for (int j = 0; j < 8; ++j) {
        int k = k16 * 16 + h * 8 + j;
        float v = 0.f;
        if (bok) {
            if (k <= 1024)       v = cosp[k];
            else if (k <= 2049)  v = ssign * sinp[k - 1025];
        }
        o[j] = f32_to_bf16(v);
    }
    #pragma unroll
    for (int j = 0; j < 8; ++j)
        Apf[(size_t)bid * 512 + l * 8 + j] = o[j];
}

// ---------------- K2: W GEMM partials ----------------
__global__ __launch_bounds__(64) void wgemm_kernel(
    const float* __restrict__ wcos, const float* __restrict__ wsin,
    const unsigned short* __restrict__ Apf, float* __restrict__ Pp)
{
    const int bid = blockIdx.x;
    const int nt = bid & 63;
    const int rest = bid >> 6;
    const int mt = rest % 6, s = rest / 6;
    const int l = threadIdx.x;
    const int c32 = l & 31, h = l >> 5;
    const int n = nt * 32 + c32;

    f32x16 acc;
    #pragma unroll
    for (int i = 0; i < 16; ++i) acc[i] = 0.f;

    const unsigned short* ap = Apf + (size_t)(mt * KP16 + s * WSLICE) * 512 + l * 8;

    for (int i = 0; i < WSLICE; ++i) {
        const int k16 = s * WSLICE + i;
        if (k16 > 128) break;
        B8 af; af.u = *(const uint4*)(ap + (size_t)i * 512);
        float bv[8];
        const int kb = k16 * 16 + h * 8;
        if (k16 <= 63) {
            #pragma unroll
            for (int j = 0; j < 8; ++j)
                bv[j] = wcos[(size_t)(kb + j) * FFTLEN + n];
        } else if (k16 >= 65 && k16 <= 127) {
            const int mb = kb - 1025;
            #pragma unroll
            for (int j = 0; j < 8; ++j)
                bv[j] = wsin[(size_t)(mb + j) * FFTLEN + n];
        } else {
            #pragma unroll
            for (int j = 0; j < 8; ++j) {
                int k = kb + j;
                float t = 0.f;
                if (k <= 1024)      t = wcos[(size_t)k * FFTLEN + n];
                else if (k <= 2049) t = wsin[(size_t)(k - 1025) * FFTLEN + n];
                bv[j] = t;
            }
        }
        acc = __builtin_amdgcn_mfma_f32_32x32x16_bf16(af.v, pack8(bv), acc, 0, 0, 0);
    }

    float* dst = Pp + (size_t)s * (192 * FFTLEN);
    #pragma unroll
    for (int r = 0; r < 16; ++r) {
        int row = mt * 32 + (r & 3) + 8 * (r >> 2) + 4 * h;
        dst[(size_t)row * FFTLEN + n] = acc[r];
    }
}

// ---------------- K3: combine partials -> Wpf (frag order) ----------------
__global__ __launch_bounds__(256) void combine_kernel(
    const float* __restrict__ Pp, unsigned short* __restrict__ Wpf)
{
    const int gid = blockIdx.x * 256 + threadIdx.x;   // < 49152
    const int mg = gid >> 13;
    const int r = gid & 8191;
    const int k16 = r >> 6, l = r & 63;
    const int c32 = l & 31, h = l >> 5;
    const int row = mg * 32 + c32;
    const int n0 = k16 * 16 + h * 8;

    float4 s0 = make_float4(0.f, 0.f, 0.f, 0.f), s1 = s0;
    const float* base = Pp + (size_t)row * FFTLEN + n0;
    #pragma unroll
    for (int s = 0; s < NSPL; ++s) {
        const float* p = base + (size_t)s * (192 * FFTLEN);
        float4 a = *(const float4*)(p);
        float4 b = *(const float4*)(p + 4);
        s0.x += a.x; s0.y += a.y; s0.z += a.z; s0.w += a.w;
        s1.x += b.x; s1.y += b.y; s1.z += b.z; s1.w += b.w;
    }
    uint4 o;
    o.x = pk_bf16(s0.x, s0.y); o.y = pk_bf16(s0.z, s0.w);
    o.z = pk_bf16(s1.x, s1.y); o.w = pk_bf16(s1.z, s1.w);
    ((uint4*)Wpf)[gid] = o;
}

// ---------------- K4: main GEMM ----------------
// grid 256 x 384 (6 waves, w = mg). Block: frames f0..f0+63, all 192 rows.
// xl layout: addr16(s) = s + 4*(s>>9) — dw-stride 258 between frames (2-way banks,
// measured 0 conflicts in R6). B frag = 2x ds_read_b64 (8B-aligned).
__global__ __launch_bounds__(384, 3) void cqt_kernel(
    const float* __restrict__ x, const unsigned short* __restrict__ Wpf,
    float* __restrict__ out)
{
    __shared__ __align__(16) unsigned short xl[XLSZ];   // 69,152 B -> 2 blocks/CU

    const int t = threadIdx.x;
    const int f0 = blockIdx.x * 64;
    const long S0 = (long)f0 * HOPS;
    const int valid = (int)((TSAMP - S0) < (long)SPAN ? (TSAMP - S0) : (long)SPAN);

    // stage x-span once: 8576 float4 over 384 threads
    #pragma unroll 1
    for (int i = 0; i < 23; ++i) {
        int idx4 = t + i * 384;
        if (idx4 < 8576) {
            int s = idx4 * 4;
            float4 v = make_float4(0.f, 0.f, 0.f, 0.f);
            if (s + 4 <= valid) v = *(const float4*)(x + S0 + s);
            ushort4 o;
            o.x = f32_to_bf16(v.x); o.y = f32_to_bf16(v.y);
            o.z = f32_to_bf16(v.z); o.w = f32_to_bf16(v.w);
            *(ushort4*)(&xl[s + 4 * (s >> 9)]) = o;
        }
    }
    __syncthreads();   // the only barrier

    const int w = t >> 6, l = t & 63;       // w = mg (0..5)
    const int c32 = l & 31, h = l >> 5;

    const unsigned short* apf = Wpf + (size_t)w * (128 * 512) + l * 8;  // + k16*512
    const int sb0 = c32 * HOPS + h * 8;            // nt=0 frame samples
    const int sb1 = (32 + c32) * HOPS + h * 8;     // nt=1

    f32x16 acc0, acc1;
    #pragma unroll
    for (int i = 0; i < 16; ++i) { acc0[i] = 0.f; acc1[i] = 0.f; }

    auto ldsB = [&](int sbase, int k16) -> bf16x8 {
        int s = sbase + k16 * 16;
        int off = s + 4 * (s >> 9);
        B8 r;
        r.p.lo = *(const ushort4*)(&xl[off]);
        r.p.hi = *(const ushort4*)(&xl[off + 4]);
        return r.v;
    };

    uint4 A0[8], A1[8];
    #pragma unroll
    for (int j = 0; j < 8; ++j)
        A0[j] = *(const uint4*)(apf + (size_t)j * 512);

    #pragma unroll 1
    for (int c = 0; c < 16; c += 2) {
        // prefetch chunk c+1 into A1 (static indices -> registers)
        #pragma unroll
        for (int j = 0; j < 8; ++j)
            A1[j] = *(const uint4*)(apf + (size_t)((c + 1) * 8 + j) * 512);
        // compute chunk c from A0
        #pragma unroll
        for (int j = 0; j < 8; ++j) {
            B8 af; af.u = A0[j];
            int k16 = c * 8 + j;
            acc0 = __builtin_amdgcn_mfma_f32_32x32x16_bf16(af.v, ldsB(sb0, k16), acc0, 0, 0, 0);
            acc1 = __builtin_amdgcn_mfma_f32_32x32x16_bf16(af.v, ldsB(sb1, k16), acc1, 0, 0, 0);
        }
        // prefetch chunk c+2 into A0
        if (c + 2 < 16) {
            #pragma unroll
            for (int j = 0; j < 8; ++j)
                A0[j] = *(const uint4*)(apf + (size_t)((c + 2) * 8 + j) * 512);
        }
        // compute chunk c+1 from A1
        #pragma unroll
        for (int j = 0; j < 8; ++j) {
            B8 af; af.u = A1[j];
            int k16 = (c + 1) * 8 + j;
            acc0 = __builtin_amdgcn_mfma_f32_32x32x16_bf16(af.v, ldsB(sb0, k16), acc0, 0, 0, 0);
            acc1 = __builtin_amdgcn_mfma_f32_32x32x16_bf16(af.v, ldsB(sb1, k16), acc1, 0, 0, 0);
        }
    }

    // epilogue: C/D col=c32 (f), row=(r&3)+8*(r>>2)+4*h; (Wr,Wi) pairs -> magnitude
    #pragma unroll
    for (int nt = 0; nt < 2; ++nt) {
        const f32x16& acc = nt ? acc1 : acc0;
        int f = f0 + nt * 32 + c32;
        if (f < NFRAMES) {
            #pragma unroll
            for (int rp = 0; rp < 4; ++rp) {
                int base = w * 32 + 8 * rp + 4 * h;   // even
                int b0 = base >> 1;
                float r0 = acc[4 * rp + 0], i0 = acc[4 * rp + 1];
                float r1 = acc[4 * rp + 2], i1 = acc[4 * rp + 3];
                if (b0 < NBINS)
                    out[(size_t)b0 * NFRAMES + f] = sqrtf(r0 * r0 + i0 * i0);
                if (b0 + 1 < NBINS)
                    out[(size_t)(b0 + 1) * NFRAMES + f] = sqrtf(r1 * r1 + i1 * i1);
            }
        }
    }
}

extern "C" void kernel_launch(void* const* d_in, const int* in_sizes, int n_in,
                              void* d_out, int out_size, void* d_ws, size_t ws_size,
                              hipStream_t stream) {
    const float* x    = (const float*)d_in[0];
    const float* wcos = (const float*)d_in[1];
    const float* wsin = (const float*)d_in[2];
    const float* kr   = (const float*)d_in[3];
    const float* ki   = (const float*)d_in[4];
    float* out = (float*)d_out;

    unsigned short* Wpf = (unsigned short*)d_ws;                    //   786,432 B
    unsigned short* Apf = (unsigned short*)((char*)d_ws + 786432);  //   847,872 B
    float* Pp = (float*)((char*)d_ws + 786432 + 847872);            // 9,437,184 B

    aprep_kernel<<<dim3(6 * KP16), dim3(64), 0, stream>>>(kr, ki, Apf);
    wgemm_kernel<<<dim3(2304), dim3(64), 0, stream>>>(wcos, wsin, Apf, Pp);
    combine_kernel<<<dim3(192), dim3(256), 0, stream>>>(Pp, Wpf);
    cqt_kernel<<<dim3(256), dim3(384), 0, stream>>>(x, Wpf, out);
}